// Round 1
// baseline (555.608 us; speedup 1.0000x reference)
//
#include <hip/hip_runtime.h>
#include <hip/hip_bf16.h>

constexpr int kB   = 4;
constexpr int kT   = 2048;
constexpr int kCIN = 2048;
constexpr int kHID = 1024;
constexpr int kEMB = 256;

typedef __bf16 bf16_t;
typedef __bf16 bf16x8 __attribute__((ext_vector_type(8)));
typedef __bf16 bf16x4 __attribute__((ext_vector_type(4)));
typedef float  f32x4  __attribute__((ext_vector_type(4)));

// async global->LDS 16B/lane (LDS dest = wave-uniform base + lane*16)
__device__ __forceinline__ void gll16(const void* g, void* l) {
  auto lp = reinterpret_cast<__attribute__((address_space(3))) uint32_t*>(
      reinterpret_cast<uintptr_t>(l));
  __builtin_amdgcn_global_load_lds(static_cast<const uint32_t*>(g), lp, 16, 0, 0);
}

#define MFMA_BF16 __builtin_amdgcn_mfma_f32_16x16x32_bf16

// ================= 256x256 8-phase double-buffered GEMM core ======================
// C[m,n] (+)= sum_k A[m,k]*B[n,k].  512 thr = 8 waves (2m x 4n), BK=64, Klen%64==0,
// Klen/64 >= 2.  LDS 128 KiB: A dbuf [2][256][64] + B dbuf [2][256][64] bf16.
// LDS reads XOR-swizzled (slot ^= row&7); global source pre-swizzled so the linear
// global_load_lds destination lands swizzled (both-sides-or-neither rule).
// B rows permuted in LDS (n -> g*128 + blk*32 + off) so each phase consumes
// call-granular 64-row regions -> prefetch of tile t+2 writes only freed regions.
// Counted vmcnt(8) once per K-tile keeps 16 loads in flight across barriers.
// MODE 0: bf16 store; MODE 2: f32 atomicAdd.
template <int MODE>
__device__ __forceinline__ void gemm256(bf16_t* lds, const bf16_t* A, const bf16_t* B,
                                        void* Cv, int lda, int ldb, int ldc,
                                        int m0, int n0, int Klen, const float* biasN) {
  const int tid  = threadIdx.x;
  const int lane = tid & 63, wv = tid >> 6;
  const int wm = wv & 1, wn = wv >> 1;
  const int lm = lane & 15, q = lane >> 4;
  const int l8 = lane >> 3;
  const int slot = (lane & 7) ^ l8;   // pre-swizzled source 16B-slot

  bf16_t* const sA = lds;
  bf16_t* const sB = lds + 32768;

  // per-thread staging source offsets (elements) for each of the 4 calls/matrix
  int aoff[4], boff[4];
#pragma unroll
  for (int cc = 0; cc < 4; cc++) {
    const int ra = cc * 64 + wv * 8 + l8;                    // lds row this thread fills
    aoff[cc] = ra * lda;                                     // A: identity row map
    const int nb = ((ra >> 5) & 3) * 64 + (ra >> 7) * 32 + (ra & 31);  // B: permuted
    boff[cc] = nb * ldb;
  }
  const bf16_t* const Ab = A + (size_t)m0 * lda + slot * 8;
  const bf16_t* const Bb = B + (size_t)n0 * ldb + slot * 8;

  const int x0 = ((q ^ (lm & 7)) << 3);        // kk=0 swizzled slot (elems)
  const int x1 = (((q + 4) ^ (lm & 7)) << 3);  // kk=1

#define STAGE_A(T, H)                                                         \
  {                                                                           \
    bf16_t* dst_ = sA + (((T) & 1) << 14);                                    \
    const bf16_t* src_ = Ab + ((T) << 6);                                     \
    gll16(src_ + aoff[(H)], dst_ + ((H) << 12) + (wv << 9));                  \
    gll16(src_ + aoff[2 + (H)], dst_ + ((2 + (H)) << 12) + (wv << 9));        \
  }
#define STAGE_B(T, G)                                                         \
  {                                                                           \
    bf16_t* dst_ = sB + (((T) & 1) << 14);                                    \
    const bf16_t* src_ = Bb + ((T) << 6);                                     \
    gll16(src_ + boff[2 * (G)], dst_ + ((2 * (G)) << 12) + (wv << 9));        \
    gll16(src_ + boff[2 * (G) + 1], dst_ + ((2 * (G) + 1) << 12) + (wv << 9));\
  }
#define READ_A(BUF, H)                                                        \
  _Pragma("unroll") for (int i = 0; i < 4; i++) {                             \
    const bf16_t* p_ = (BUF) + ((wm * 128 + (H) * 64 + i * 16 + lm) << 6);    \
    af[i][0] = *(const bf16x8*)(p_ + x0);                                     \
    af[i][1] = *(const bf16x8*)(p_ + x1);                                     \
  }
#define READ_B(BF, BUF, G)                                                    \
  _Pragma("unroll") for (int j2 = 0; j2 < 2; j2++) {                          \
    const bf16_t* p_ = (BUF) + (((G) * 128 + wn * 32 + j2 * 16 + lm) << 6);   \
    BF[j2][0] = *(const bf16x8*)(p_ + x0);                                    \
    BF[j2][1] = *(const bf16x8*)(p_ + x1);                                    \
  }
#define QUAD(H, G, BF)                                                        \
  _Pragma("unroll") for (int i2 = 0; i2 < 4; i2++)                            \
  _Pragma("unroll") for (int j2 = 0; j2 < 2; j2++)                            \
  _Pragma("unroll") for (int kk = 0; kk < 2; kk++)                            \
    acc[(H) * 4 + i2][(G) * 2 + j2] = MFMA_BF16(                              \
        af[i2][kk], BF[j2][kk], acc[(H) * 4 + i2][(G) * 2 + j2], 0, 0, 0);

  f32x4 acc[8][4];
#pragma unroll
  for (int i = 0; i < 8; i++)
#pragma unroll
    for (int j = 0; j < 4; j++)
#pragma unroll
      for (int r = 0; r < 4; r++) acc[i][j][r] = 0.f;

  const int nt = Klen >> 6;

  // prologue: stage tiles 0 and 1 (8 calls each, order A0,B0,B1,A1)
  STAGE_A(0, 0) STAGE_B(0, 0) STAGE_B(0, 1) STAGE_A(0, 1)
  STAGE_A(1, 0) STAGE_B(1, 0) STAGE_B(1, 1) STAGE_A(1, 1)
  asm volatile("s_waitcnt vmcnt(8)" ::: "memory");  // oldest 8 = tile0 done
  __builtin_amdgcn_s_barrier();

  bf16x8 af[4][2], bf0[2][2], bf1[2][2];
  for (int t = 0; t < nt; t++) {
    bf16_t* const a = sA + ((t & 1) << 14);
    bf16_t* const b = sB + ((t & 1) << 14);
    const bool pf = (t + 2) < nt;
    // P1: read A-half0 + B-group0; MFMA quadrant (m0,n0)
    READ_A(a, 0)
    READ_B(bf0, b, 0)
    __builtin_amdgcn_s_barrier();
    __builtin_amdgcn_s_setprio(1);
    QUAD(0, 0, bf0)
    __builtin_amdgcn_s_setprio(0);
    asm volatile("s_waitcnt lgkmcnt(0)" ::: "memory");
    __builtin_amdgcn_s_barrier();
    // P2: read B-group1; prefetch A-half0(t+2) into region freed at P1
    READ_B(bf1, b, 1)
    if (pf) STAGE_A(t + 2, 0)
    __builtin_amdgcn_s_barrier();
    __builtin_amdgcn_s_setprio(1);
    QUAD(0, 1, bf1)
    __builtin_amdgcn_s_setprio(0);
    asm volatile("s_waitcnt lgkmcnt(0)" ::: "memory");
    __builtin_amdgcn_s_barrier();
    // P3: read A-half1; prefetch B-group0(t+2) (freed at P1)
    READ_A(a, 1)
    if (pf) STAGE_B(t + 2, 0)
    __builtin_amdgcn_s_barrier();
    __builtin_amdgcn_s_setprio(1);
    QUAD(1, 1, bf1)
    __builtin_amdgcn_s_setprio(0);
    asm volatile("s_waitcnt lgkmcnt(0)" ::: "memory");
    __builtin_amdgcn_s_barrier();
    // P4: prefetch B-group1(t+2) (freed P2) + A-half1(t+2) (freed P3); reg-only MFMA
    if (pf) { STAGE_B(t + 2, 1) STAGE_A(t + 2, 1) }
    __builtin_amdgcn_s_barrier();
    __builtin_amdgcn_s_setprio(1);
    QUAD(1, 0, bf0)
    __builtin_amdgcn_s_setprio(0);
    if (pf)
      asm volatile("s_waitcnt vmcnt(8)" ::: "memory");   // tile t+1 fully landed
    else if (t + 1 < nt)
      asm volatile("s_waitcnt vmcnt(0)" ::: "memory");   // drain for last tile
    __builtin_amdgcn_s_barrier();
  }

  // epilogue: C/D layout col=lane&15, row=(lane>>4)*4+reg
#pragma unroll
  for (int i = 0; i < 8; i++) {
    const int gm = m0 + wm * 128 + (i >> 2) * 64 + (i & 3) * 16 + q * 4;
#pragma unroll
    for (int j = 0; j < 4; j++) {
      const int gn = n0 + wn * 64 + j * 16 + lm;
      const float bn_ = biasN ? biasN[gn] : 0.f;
#pragma unroll
      for (int r = 0; r < 4; r++) {
        const float v = acc[i][j][r] + bn_;
        const size_t idx = (size_t)(gm + r) * ldc + gn;
        if (MODE == 0) ((bf16_t*)Cv)[idx] = (bf16_t)v;
        else           atomicAdd(&((float*)Cv)[idx], v);
      }
    }
  }
#undef STAGE_A
#undef STAGE_B
#undef READ_A
#undef READ_B
#undef QUAD
}

// ================= dispatch 1: prep (casts + wwT + biases) + zero(out) ============
__global__ __launch_bounds__(256) void k_prep(const float* __restrict__ x,
                                              const float* __restrict__ th,
                                              const float* __restrict__ ph,
                                              const float* __restrict__ g,
                                              const float* __restrict__ emb,
                                              const float* __restrict__ w_w,
                                              const float* __restrict__ w_b,
                                              const float* __restrict__ emb_b,
                                              const float* __restrict__ tb,
                                              const float* __restrict__ pb,
                                              const float* __restrict__ gb,
                                              bf16_t* __restrict__ xbf,
                                              bf16_t* __restrict__ wqkv,
                                              bf16_t* __restrict__ embbf,
                                              bf16_t* __restrict__ wwT,
                                              float* __restrict__ biase,
                                              float* __restrict__ bqkv,
                                              float* __restrict__ out) {
  __shared__ float tile[64 * 66];
  const int b = blockIdx.x;
  if (b < 23040) {  // casts
    const float* in; bf16_t* o; long i;
    if (b < 16384)      { in = x;   o = xbf;                            i = (long)b * 256 + threadIdx.x; }
    else if (b < 18432) { in = th;  o = wqkv;                           i = (long)(b - 16384) * 256 + threadIdx.x; }
    else if (b < 20480) { in = ph;  o = wqkv + (size_t)kHID * kCIN;     i = (long)(b - 18432) * 256 + threadIdx.x; }
    else if (b < 22528) { in = g;   o = wqkv + (size_t)2 * kHID * kCIN; i = (long)(b - 20480) * 256 + threadIdx.x; }
    else                { in = emb; o = embbf;                          i = (long)(b - 22528) * 256 + threadIdx.x; }
    float4 v = ((const float4*)in)[i];
    bf16x4 ov;
    ov[0] = (bf16_t)v.x; ov[1] = (bf16_t)v.y; ov[2] = (bf16_t)v.z; ov[3] = (bf16_t)v.w;
    ((bf16x4*)o)[i] = ov;
  } else if (b < 23552) {  // w_w (CIN,HID) -> wwT (HID,CIN), 64x64 tiles
    int j = b - 23040;
    int h0 = (j & 15) * 64, c0 = (j >> 4) * 64;
#pragma unroll
    for (int k = 0; k < 16; k++) {
      int e = k * 256 + threadIdx.x;
      int r = e >> 6, c = e & 63;
      tile[r * 66 + c] = w_w[(size_t)(c0 + r) * kHID + h0 + c];
    }
    __syncthreads();
#pragma unroll
    for (int k = 0; k < 16; k++) {
      int e = k * 256 + threadIdx.x;
      int r = e >> 6, c = e & 63;
      wwT[(size_t)(h0 + r) * kCIN + c0 + c] = (bf16_t)tile[c * 66 + r];
    }
  } else if (b < 23808) {  // bias_e
    int e = b - 23552;
    float acc = 0.f;
    for (int c = threadIdx.x; c < kCIN; c += 256)
      acc += emb[(size_t)e * kCIN + c] * w_b[c];
#pragma unroll
    for (int o = 32; o > 0; o >>= 1) acc += __shfl_xor(acc, o, 64);
    __syncthreads();
    if ((threadIdx.x & 63) == 0) tile[threadIdx.x >> 6] = acc;
    __syncthreads();
    if (threadIdx.x == 0) biase[e] = tile[0] + tile[1] + tile[2] + tile[3] + emb_b[e];
  } else if (b < 23820) {  // concat biases -> bqkv[3072]
    int i = (b - 23808) * 256 + threadIdx.x;
    if (i < 3072)
      bqkv[i] = i < 1024 ? tb[i] : (i < 2048 ? pb[i - 1024] : gb[i - 2048]);
  } else {  // zero d_out (2M f32 = 524288 float4)
    long i = (long)(b - 23820) * 256 + threadIdx.x;
    ((float4*)out)[i] = make_float4(0.f, 0.f, 0.f, 0.f);
  }
}

// ====== dispatch 2: QKV(384) + S1-tri(144) + M(4) as 512 balanced blocks, =========
// ====== plus x@emb^T split-K4 atomic (128 small blocks as backfill) ===============
__global__ __launch_bounds__(512, 2) void k_mega1(const bf16_t* __restrict__ xbf,
                                                  const bf16_t* __restrict__ wqkv,
                                                  const bf16_t* __restrict__ embbf,
                                                  const bf16_t* __restrict__ wwT,
                                                  bf16_t* __restrict__ xtphi,
                                                  bf16_t* __restrict__ S1,
                                                  bf16_t* __restrict__ Mbf,
                                                  const float* __restrict__ bqkv,
                                                  float* __restrict__ out,
                                                  const float* __restrict__ biase) {
  __shared__ bf16_t lds[65536];  // 128 KiB
  const int bid = blockIdx.x;
  if (bid >= 512) {  // small: out += x @ emb^T (K=512 slices), + biase on slice 0
    const int r = bid - 512;
    const int bm = r & 31, ks = r >> 5;
    gemm256<2>(lds, xbf + ks * 512, embbf + ks * 512, out, 2048, 2048, 256,
               bm * 256, 0, 512, ks == 0 ? biase : nullptr);
    return;
  }
  // 532 uniform K=2048 tiles on 512 blocks: blocks 0..19 take two tiles (492..531)
  const int reps = (bid < 20) ? 2 : 1;
  const int tile0 = (bid < 20) ? (492 + 2 * bid) : (bid - 20);
  for (int rep = 0; rep < reps; rep++) {
    if (rep) __syncthreads();
    const int tile = tile0 + rep;
    if (tile < 384) {  // xtphi = x @ wqkv^T + bqkv (8192 x 3072, K=2048)
      const int bm = tile & 31, bn = tile >> 5;
      gemm256<0>(lds, xbf, wqkv, xtphi, 2048, 2048, 3072,
                 bm * 256, bn * 256, 2048, bqkv);
    } else if (tile < 528) {  // S1[z] = x[z] @ x[z]^T, upper triangular 256-tiles
      int s = tile - 384;
      const int z = s / 36;
      int tt = s % 36, rr = 0;
      while (tt >= 8 - rr) { tt -= 8 - rr; rr++; }
      const bf16_t* Az = xbf + (size_t)z * kT * kCIN;
      gemm256<0>(lds, Az, Az, S1 + (size_t)z * kT * kT, 2048, 2048, 2048,
                 rr * 256, (rr + tt) * 256, 2048, nullptr);
    } else {  // M = emb @ w_w (256 x 1024, K=2048)
      const int m = tile - 528;
      gemm256<0>(lds, embbf, wwT, Mbf, 2048, 2048, 1024, 0, m * 256, 2048, nullptr);
    }
  }
}

// ================= dispatch 3: S2 (256 blocks = exactly 1 round) ==================
__global__ __launch_bounds__(512, 2) void k_gemm2(const bf16_t* __restrict__ xtphi,
                                                  bf16_t* __restrict__ S2) {
  __shared__ bf16_t lds[65536];
  const int bid = blockIdx.x;
  const int bm = bid & 7, bn = (bid >> 3) & 7, z = bid >> 6;
  const bf16_t* base = xtphi + (size_t)z * kT * 3072;
  gemm256<0>(lds, base + 1024, base, S2 + (size_t)z * kT * kT, 3072, 3072, 2048,
             bm * 256, bn * 256, 1024, nullptr);
}

// ====== dispatch 4: mirror S1 (1984) + xg-transpose (2048), 256-thread blocks =====
__global__ __launch_bounds__(256) void k_util(bf16_t* __restrict__ S1,
                                              const bf16_t* __restrict__ xtphi,
                                              bf16_t* __restrict__ xgT) {
  __shared__ bf16_t tile[64 * 66];
  const int bid = blockIdx.x;
  const size_t T2 = (size_t)kT * kT;
  if (bid < 1984) {  // mirror S1 upper -> lower (64x64 tiles, p>q)
    int z = bid / 496, t = bid % 496, qq = 0;
    while (t >= 31 - qq) { t -= 31 - qq; qq++; }
    int p = qq + 1 + t;
    const size_t base = (size_t)z * T2;
#pragma unroll
    for (int k = 0; k < 16; k++) {
      int e = k * 256 + threadIdx.x;
      int r = e >> 6, c = e & 63;
      tile[r * 66 + c] = S1[base + (size_t)(qq * 64 + r) * kT + p * 64 + c];
    }
    __syncthreads();
#pragma unroll
    for (int k = 0; k < 16; k++) {
      int e = k * 256 + threadIdx.x;
      int r = e >> 6, c = e & 63;
      S1[base + (size_t)(p * 64 + r) * kT + qq * 64 + c] = tile[c * 66 + r];
    }
  } else {  // xgT[z](h,t) from xg slice of xtphi
    int j = bid - 1984;
    int hb = j & 15, tb2 = (j >> 4) & 31, z = j >> 9;
#pragma unroll
    for (int k = 0; k < 16; k++) {
      int e = k * 256 + threadIdx.x;
      int r = e >> 6, c = e & 63;  // r: t, c: h
      tile[r * 66 + c] = xtphi[(size_t)(z * kT + tb2 * 64 + r) * 3072 + 2048 + hb * 64 + c];
    }
    __syncthreads();
#pragma unroll
    for (int k = 0; k < 16; k++) {
      int e = k * 256 + threadIdx.x;
      int r = e >> 6, c = e & 63;  // r: h, c: t
      xgT[(size_t)z * kHID * kT + (size_t)(hb * 64 + r) * kT + tb2 * 64 + c] = tile[c * 66 + r];
    }
  }
}

// ================= dispatch 5: moca (both softmax passes) =========================
__global__ __launch_bounds__(256) void k_moca(const bf16_t* __restrict__ S1,
                                              const bf16_t* __restrict__ S2,
                                              bf16_t* __restrict__ dst,
                                              const float* __restrict__ rou_w,
                                              const float* __restrict__ rou_b) {
  __shared__ float s[4];
  const int t = blockIdx.x, b = blockIdx.y;
  const size_t T2 = (size_t)kT * kT;
  const bf16_t* src = (b < 2) ? S1 : S2;
  const int pb = (b < 2) ? 2 * b : 2 * (b - 2);
  const bf16_t* rA = src + (size_t)pb * T2 + (size_t)t * kT;
  const bf16_t* rB = rA + T2;
  const int base = threadIdx.x * 8;

  float va[8], vb[8];
  {
    bf16x8 a = *(const bf16x8*)(rA + base);
    bf16x8 bb = *(const bf16x8*)(rB + base);
#pragma unroll
    for (int j = 0; j < 8; j++) { va[j] = (float)a[j]; vb[j] = (float)bb[j]; }
  }
  auto red_max = [&](float v) {
#pragma unroll
    for (int o = 32; o > 0; o >>= 1) v = fmaxf(v, __shfl_xor(v, o, 64));
    __syncthreads();
    if ((threadIdx.x & 63) == 0) s[threadIdx.x >> 6] = v;
    __syncthreads();
    return fmaxf(fmaxf(s[0], s[1]), fmaxf(s[2], s[3]));
  };
  auto red_sum = [&](float v) {
#pragma unroll
    for (int o = 32; o > 0; o >>= 1) v += __shfl_xor(v, o, 64);
    __syncthreads();
    if ((threadIdx.x & 63) == 0) s[threadIdx.x >> 6] = v;
    __syncthreads();
    return (s[0] + s[1]) + (s[2] + s[3]);
  };

  float m = -1e30f, acc;
#pragma unroll
  for (int j = 0; j < 8; j++) m = fmaxf(m, va[j]);
  m = red_max(m); acc = 0.f;
#pragma unroll
  for (int j = 0; j < 8; j++) { va[j] = __expf(va[j] - m); acc += va[j]; }
  float invA = 1.f / red_sum(acc);

  m = -1e30f;
#pragma unroll
  for (int j = 0; j < 8; j++) m = fmaxf(m, vb[j]);
  m = red_max(m); acc = 0.f;
#pragma unroll
  for (int j = 0; j < 8; j++) { vb[j] = __expf(vb[j] - m); acc += vb[j]; }
  float invB = 1.f / red_sum(acc);

  const float r0 = rou_w[0], r1 = rou_w[1], rb = rou_b[0];
#pragma unroll
  for (int j = 0; j < 8; j++) va[j] = r0 * va[j] * invA + r1 * vb[j] * invB + rb;

  m = -1e30f;
#pragma unroll
  for (int j = 0; j < 8; j++) m = fmaxf(m, va[j]);
  m = red_max(m); acc = 0.f;
#pragma unroll
  for (int j = 0; j < 8; j++) { va[j] = __expf(va[j] - m); acc += va[j]; }
  float invC = 1.f / red_sum(acc);

  bf16x8 o;
#pragma unroll
  for (int j = 0; j < 8; j++) o[j] = (bf16_t)(va[j] * invC);
  *(bf16x8*)(dst + (size_t)b * T2 + (size_t)t * kT + base) = o;
}

// ================= dispatch 6: mocab -> mocaT (batched TxT transpose) =============
__global__ __launch_bounds__(256) void k_mocaT(const bf16_t* __restrict__ in,
                                               bf16_t* __restrict__ out) {
  __shared__ bf16_t tile[64 * 66];
  size_t base = (size_t)blockIdx.z * kT * kT;
  int r0 = blockIdx.y * 64, c0 = blockIdx.x * 64;
#pragma unroll
  for (int k = 0; k < 16; k++) {
    int e = k * 256 + threadIdx.x;
    int r = e >> 6, c = e & 63;
    tile[r * 66 + c] = in[base + (size_t)(r0 + r) * kT + c0 + c];
  }
  __syncthreads();
#pragma unroll
  for (int k = 0; k < 16; k++) {
    int e = k * 256 + threadIdx.x;
    int r = e >> 6, c = e & 63;
    out[base + (size_t)(c0 + r) * kT + r0 + c] = tile[c * 66 + r];
  }
}

// ================= dispatch 7: yT = mocaT @ xgT^T (128 blocks, K=2048) ============
__global__ __launch_bounds__(512, 2) void k_tail1(const bf16_t* __restrict__ mocaT,
                                                  const bf16_t* __restrict__ xgT,
                                                  bf16_t* __restrict__ yT) {
  __shared__ bf16_t lds[65536];
  const int bid = blockIdx.x;
  const int bm = bid & 7, bn = (bid >> 3) & 3, z = bid >> 5;
  gemm256<0>(lds, mocaT + (size_t)z * kT * kT, xgT + (size_t)z * kHID * kT,
             yT + (size_t)z * kT * kHID, 2048, 2048, 1024,
             bm * 256, bn * 256, 2048, nullptr);
}

// ================= dispatch 8: out += yT @ M^T split-K4 atomic (128) ==============
__global__ __launch_bounds__(512, 2) void k_tail2(const bf16_t* __restrict__ yT,
                                                  const bf16_t* __restrict__ Mbf,
                                                  float* __restrict__ out) {
  __shared__ bf16_t lds[65536];
  const int bid = blockIdx.x;
  const int bm = bid & 31, ks = bid >> 5;
  gemm256<2>(lds, yT + ks * 256, Mbf + ks * 256, out, 1024, 1024, 256,
             bm * 256, 0, 256, nullptr);
}

extern "C" void kernel_launch(void* const* d_in, const int* in_sizes, int n_in,
                              void* d_out, int out_size, void* d_ws, size_t ws_size,
                              hipStream_t stream) {
  const float* x       = (const float*)d_in[0];
  const float* theta_w = (const float*)d_in[1];
  const float* theta_b = (const float*)d_in[2];
  const float* phi_w   = (const float*)d_in[3];
  const float* phi_b   = (const float*)d_in[4];
  const float* g_w     = (const float*)d_in[5];
  const float* g_b     = (const float*)d_in[6];
  const float* rou_w   = (const float*)d_in[7];
  const float* rou_b   = (const float*)d_in[8];
  const float* w_w     = (const float*)d_in[9];
  const float* w_b     = (const float*)d_in[10];
  const float* emb_w   = (const float*)d_in[11];
  const float* emb_b   = (const float*)d_in[12];
  float* out = (float*)d_out;

  char* ws = (char*)d_ws;
  size_t off = 0;
  auto alloc = [&](size_t bytes) -> char* {
    off = (off + 255) & ~(size_t)255;
    char* p = ws + off;
    off += bytes;
    return p;
  };

  const size_t BT = (size_t)kB * kT;   // 8192
  const size_t T2 = (size_t)kT * kT;   // 4M

  bf16_t* xbf   = (bf16_t*)alloc(BT * kCIN * 2);               // 33.5 MB
  bf16_t* wqkv  = (bf16_t*)alloc((size_t)3 * kHID * kCIN * 2); // 12.6 MB
  bf16_t* embbf = (bf16_t*)alloc((size_t)kEMB * kCIN * 2);     // 1.0 MB
  bf16_t* wwT   = (bf16_t*)alloc((size_t)kHID * kCIN * 2);     // 4.2 MB
  bf16_t* xtphi = (bf16_t*)alloc(BT * 3072 * 2);               // 50.3 MB [xt|xphi|xg]
  bf16_t* xgT   = (bf16_t*)alloc((size_t)kB * kHID * kT * 2);  // 16.8 MB
  bf16_t* mocab = (bf16_t*)alloc((size_t)kB * T2 * 2);         // 33.5 MB
  bf16_t* Mbf   = (bf16_t*)alloc((size_t)kEMB * kHID * 2);     // 0.5 MB
  float*  biase = (float*)alloc((size_t)kEMB * 4);
  float*  bqkv  = (float*)alloc((size_t)3072 * 4);
  bf16_t* S1    = (bf16_t*)alloc((size_t)kB * T2 * 2);         // 33.5 MB
  bf16_t* S2    = (bf16_t*)alloc((size_t)kB * T2 * 2);         // 33.5 MB
  // aliases over dead regions:
  bf16_t* mocaT = (bf16_t*)xtphi;  // xtphi dead after k_gemm2 + k_util(xgT)
  bf16_t* yT    = (bf16_t*)S2;     // S2 dead after k_moca (16.8 <= 33.5)

  // 1: prep (casts + wwT + bias_e + bqkv + zero(out))
  k_prep<<<dim3(25868), 256, 0, stream>>>(x, theta_w, phi_w, g_w, emb_w, w_w, w_b,
                                          emb_b, theta_b, phi_b, g_b,
                                          xbf, wqkv, embbf, wwT, biase, bqkv, out);
  // 2: QKV + S1-triangular + M (balanced 512) + x@emb^T split-K backfill (128)
  k_mega1<<<dim3(640), 512, 0, stream>>>(xbf, wqkv, embbf, wwT, xtphi, S1, Mbf,
                                         bqkv, out, biase);
  // 3: S2
  k_gemm2<<<dim3(256), 512, 0, stream>>>(xtphi, S2);
  // 4: mirror(S1) + xgT
  k_util<<<dim3(4032), 256, 0, stream>>>(S1, xtphi, xgT);
  // 5: moca (both passes)
  k_moca<<<dim3(kT, kB), 256, 0, stream>>>(S1, S2, mocab, rou_w, rou_b);
  // 6: mocaT (overwrites dead xtphi)
  k_mocaT<<<dim3(32, 32, kB), 256, 0, stream>>>(mocab, mocaT);
  // 7: yT GEMM (over dead S2)
  k_tail1<<<dim3(128), 512, 0, stream>>>(mocaT, xgT, yT);
  // 8: out += yT @ M^T split-K atomic
  k_tail2<<<dim3(128), 512, 0, stream>>>(yT, Mbf, out);
}

// Round 2
// 485.560 us; speedup vs baseline: 1.1443x; 1.1443x over previous
//
#include <hip/hip_runtime.h>
#include <hip/hip_bf16.h>

constexpr int kB   = 4;
constexpr int kT   = 2048;
constexpr int kCIN = 2048;
constexpr int kHID = 1024;
constexpr int kEMB = 256;

typedef __bf16 bf16_t;
typedef __bf16 bf16x8 __attribute__((ext_vector_type(8)));
typedef __bf16 bf16x4 __attribute__((ext_vector_type(4)));
typedef float  f32x4  __attribute__((ext_vector_type(4)));

// async global->LDS 16B/lane (LDS dest = wave-uniform base + lane*16)
__device__ __forceinline__ void gll16(const void* g, void* l) {
  auto lp = reinterpret_cast<__attribute__((address_space(3))) uint32_t*>(
      reinterpret_cast<uintptr_t>(l));
  __builtin_amdgcn_global_load_lds(static_cast<const uint32_t*>(g), lp, 16, 0, 0);
}

#define MFMA_BF16 __builtin_amdgcn_mfma_f32_16x16x32_bf16

// ================= 256x256 8-phase double-buffered GEMM core ======================
// C[m,n] (+)= sum_k A[m,k]*B[n,k].  512 thr = 8 waves (2m x 4n), BK=64, Klen%64==0,
// Klen/64 >= 2.  LDS 128 KiB: A dbuf [2][256][64] + B dbuf [2][256][64] bf16.
// LDS reads XOR-swizzled (slot ^= row&7); global source pre-swizzled so the linear
// global_load_lds destination lands swizzled (both-sides-or-neither rule).
// B rows permuted in LDS (n -> g*128 + blk*32 + off) so each phase consumes
// call-granular 64-row regions -> prefetch of tile t+2 writes only freed regions.
// Counted vmcnt(8) once per K-tile keeps 16 loads in flight across barriers.
// Phases sealed with sched_barrier(0) (rule #18/#19: raw s_barrier is NOT a
// compiler fence; MFMAs/reads migrate across and collapse the interleave).
// MODE 0: bf16 store; MODE 2: f32 atomicAdd.
template <int MODE>
__device__ __forceinline__ void gemm256(bf16_t* lds, const bf16_t* A, const bf16_t* B,
                                        void* Cv, int lda, int ldb, int ldc,
                                        int m0, int n0, int Klen, const float* biasN) {
  const int tid  = threadIdx.x;
  const int lane = tid & 63, wv = tid >> 6;
  const int wm = wv & 1, wn = wv >> 1;
  const int lm = lane & 15, q = lane >> 4;
  const int l8 = lane >> 3;
  const int slot = (lane & 7) ^ l8;   // pre-swizzled source 16B-slot

  bf16_t* const sA = lds;
  bf16_t* const sB = lds + 32768;

  // per-thread staging source offsets (elements) for each of the 4 calls/matrix
  int aoff[4], boff[4];
#pragma unroll
  for (int cc = 0; cc < 4; cc++) {
    const int ra = cc * 64 + wv * 8 + l8;                    // lds row this thread fills
    aoff[cc] = ra * lda;                                     // A: identity row map
    const int nb = ((ra >> 5) & 3) * 64 + (ra >> 7) * 32 + (ra & 31);  // B: permuted
    boff[cc] = nb * ldb;
  }
  const bf16_t* const Ab = A + (size_t)m0 * lda + slot * 8;
  const bf16_t* const Bb = B + (size_t)n0 * ldb + slot * 8;

  const int x0 = ((q ^ (lm & 7)) << 3);        // kk=0 swizzled slot (elems)
  const int x1 = (((q + 4) ^ (lm & 7)) << 3);  // kk=1

#define STAGE_A(T, H)                                                         \
  {                                                                           \
    bf16_t* dst_ = sA + (((T) & 1) << 14);                                    \
    const bf16_t* src_ = Ab + ((T) << 6);                                     \
    gll16(src_ + aoff[(H)], dst_ + ((H) << 12) + (wv << 9));                  \
    gll16(src_ + aoff[2 + (H)], dst_ + ((2 + (H)) << 12) + (wv << 9));        \
  }
#define STAGE_B(T, G)                                                         \
  {                                                                           \
    bf16_t* dst_ = sB + (((T) & 1) << 14);                                    \
    const bf16_t* src_ = Bb + ((T) << 6);                                     \
    gll16(src_ + boff[2 * (G)], dst_ + ((2 * (G)) << 12) + (wv << 9));        \
    gll16(src_ + boff[2 * (G) + 1], dst_ + ((2 * (G) + 1) << 12) + (wv << 9));\
  }
#define READ_A(BUF, H)                                                        \
  _Pragma("unroll") for (int i = 0; i < 4; i++) {                             \
    const bf16_t* p_ = (BUF) + ((wm * 128 + (H) * 64 + i * 16 + lm) << 6);    \
    af[i][0] = *(const bf16x8*)(p_ + x0);                                     \
    af[i][1] = *(const bf16x8*)(p_ + x1);                                     \
  }
#define READ_B(BF, BUF, G)                                                    \
  _Pragma("unroll") for (int j2 = 0; j2 < 2; j2++) {                          \
    const bf16_t* p_ = (BUF) + (((G) * 128 + wn * 32 + j2 * 16 + lm) << 6);   \
    BF[j2][0] = *(const bf16x8*)(p_ + x0);                                    \
    BF[j2][1] = *(const bf16x8*)(p_ + x1);                                    \
  }
#define QUAD(H, G, BF)                                                        \
  _Pragma("unroll") for (int i2 = 0; i2 < 4; i2++)                            \
  _Pragma("unroll") for (int j2 = 0; j2 < 2; j2++)                            \
  _Pragma("unroll") for (int kk = 0; kk < 2; kk++)                            \
    acc[(H) * 4 + i2][(G) * 2 + j2] = MFMA_BF16(                              \
        af[i2][kk], BF[j2][kk], acc[(H) * 4 + i2][(G) * 2 + j2], 0, 0, 0);
#define SEAL() __builtin_amdgcn_sched_barrier(0)
#define MFMA_OPEN()                                                           \
  asm volatile("s_waitcnt lgkmcnt(0)" ::: "memory");                          \
  SEAL();                                                                     \
  __builtin_amdgcn_s_setprio(1);
#define MFMA_CLOSE()                                                          \
  __builtin_amdgcn_s_setprio(0);                                              \
  SEAL();

  f32x4 acc[8][4];
#pragma unroll
  for (int i = 0; i < 8; i++)
#pragma unroll
    for (int j = 0; j < 4; j++)
#pragma unroll
      for (int r = 0; r < 4; r++) acc[i][j][r] = 0.f;

  const int nt = Klen >> 6;

  // prologue: stage tiles 0 and 1 (8 calls each)
  STAGE_A(0, 0) STAGE_B(0, 0) STAGE_B(0, 1) STAGE_A(0, 1)
  STAGE_A(1, 0) STAGE_B(1, 0) STAGE_B(1, 1) STAGE_A(1, 1)
  asm volatile("s_waitcnt vmcnt(8)" ::: "memory");  // oldest 8 = tile0 done
  __builtin_amdgcn_s_barrier();
  SEAL();

  bf16x8 af[4][2], bf0[2][2], bf1[2][2];
  for (int t = 0; t < nt; t++) {
    bf16_t* const a = sA + ((t & 1) << 14);
    bf16_t* const b = sB + ((t & 1) << 14);
    const bool pf = (t + 2) < nt;
    // P1: read A-half0 + B-group0 (12 b128); MFMA quadrant (0,0)
    READ_A(a, 0)
    READ_B(bf0, b, 0)
    asm volatile("s_waitcnt lgkmcnt(8)" ::: "memory");  // throttle (12-read phase)
    __builtin_amdgcn_s_barrier();
    MFMA_OPEN()
    QUAD(0, 0, bf0)
    MFMA_CLOSE()
    __builtin_amdgcn_s_barrier();
    // P2: read B-group1 (4 b128); prefetch A-half0(t+2) into region freed at P1
    READ_B(bf1, b, 1)
    if (pf) STAGE_A(t + 2, 0)
    SEAL();
    __builtin_amdgcn_s_barrier();
    MFMA_OPEN()
    QUAD(0, 1, bf1)
    MFMA_CLOSE()
    __builtin_amdgcn_s_barrier();
    // P3: read A-half1 (8 b128); prefetch B-group0(t+2) (freed at P1)
    READ_A(a, 1)
    if (pf) STAGE_B(t + 2, 0)
    SEAL();
    __builtin_amdgcn_s_barrier();
    MFMA_OPEN()
    QUAD(1, 1, bf1)
    MFMA_CLOSE()
    __builtin_amdgcn_s_barrier();
    // P4: prefetch B-group1(t+2) (freed P2) + A-half1(t+2) (freed P3); reg-only MFMA
    if (pf) { STAGE_B(t + 2, 1) STAGE_A(t + 2, 1) }
    SEAL();
    __builtin_amdgcn_s_barrier();
    SEAL();
    __builtin_amdgcn_s_setprio(1);
    QUAD(1, 0, bf0)
    __builtin_amdgcn_s_setprio(0);
    SEAL();
    if (pf)
      asm volatile("s_waitcnt vmcnt(8)" ::: "memory");   // tile t+1 fully landed
    else if (t + 1 < nt)
      asm volatile("s_waitcnt vmcnt(0)" ::: "memory");   // drain for last tile
    __builtin_amdgcn_s_barrier();
    SEAL();
  }

  // epilogue: C/D layout col=lane&15, row=(lane>>4)*4+reg
#pragma unroll
  for (int i = 0; i < 8; i++) {
    const int gm = m0 + wm * 128 + (i >> 2) * 64 + (i & 3) * 16 + q * 4;
#pragma unroll
    for (int j = 0; j < 4; j++) {
      const int gn = n0 + wn * 64 + j * 16 + lm;
      const float bn_ = biasN ? biasN[gn] : 0.f;
#pragma unroll
      for (int r = 0; r < 4; r++) {
        const float v = acc[i][j][r] + bn_;
        const size_t idx = (size_t)(gm + r) * ldc + gn;
        if (MODE == 0) ((bf16_t*)Cv)[idx] = (bf16_t)v;
        else           atomicAdd(&((float*)Cv)[idx], v);
      }
    }
  }
#undef STAGE_A
#undef STAGE_B
#undef READ_A
#undef READ_B
#undef QUAD
#undef SEAL
#undef MFMA_OPEN
#undef MFMA_CLOSE
}

// ================= dispatch 1: prep (casts + wwT + biases) + zero(out) ============
__global__ __launch_bounds__(256) void k_prep(const float* __restrict__ x,
                                              const float* __restrict__ th,
                                              const float* __restrict__ ph,
                                              const float* __restrict__ g,
                                              const float* __restrict__ emb,
                                              const float* __restrict__ w_w,
                                              const float* __restrict__ w_b,
                                              const float* __restrict__ emb_b,
                                              const float* __restrict__ tb,
                                              const float* __restrict__ pb,
                                              const float* __restrict__ gb,
                                              bf16_t* __restrict__ xbf,
                                              bf16_t* __restrict__ wqkv,
                                              bf16_t* __restrict__ embbf,
                                              bf16_t* __restrict__ wwT,
                                              float* __restrict__ biase,
                                              float* __restrict__ bqkv,
                                              float* __restrict__ out) {
  __shared__ float tile[64 * 66];
  const int b = blockIdx.x;
  if (b < 23040) {  // casts
    const float* in; bf16_t* o; long i;
    if (b < 16384)      { in = x;   o = xbf;                            i = (long)b * 256 + threadIdx.x; }
    else if (b < 18432) { in = th;  o = wqkv;                           i = (long)(b - 16384) * 256 + threadIdx.x; }
    else if (b < 20480) { in = ph;  o = wqkv + (size_t)kHID * kCIN;     i = (long)(b - 18432) * 256 + threadIdx.x; }
    else if (b < 22528) { in = g;   o = wqkv + (size_t)2 * kHID * kCIN; i = (long)(b - 20480) * 256 + threadIdx.x; }
    else                { in = emb; o = embbf;                          i = (long)(b - 22528) * 256 + threadIdx.x; }
    float4 v = ((const float4*)in)[i];
    bf16x4 ov;
    ov[0] = (bf16_t)v.x; ov[1] = (bf16_t)v.y; ov[2] = (bf16_t)v.z; ov[3] = (bf16_t)v.w;
    ((bf16x4*)o)[i] = ov;
  } else if (b < 23552) {  // w_w (CIN,HID) -> wwT (HID,CIN), 64x64 tiles
    int j = b - 23040;
    int h0 = (j & 15) * 64, c0 = (j >> 4) * 64;
#pragma unroll
    for (int k = 0; k < 16; k++) {
      int e = k * 256 + threadIdx.x;
      int r = e >> 6, c = e & 63;
      tile[r * 66 + c] = w_w[(size_t)(c0 + r) * kHID + h0 + c];
    }
    __syncthreads();
#pragma unroll
    for (int k = 0; k < 16; k++) {
      int e = k * 256 + threadIdx.x;
      int r = e >> 6, c = e & 63;
      wwT[(size_t)(h0 + r) * kCIN + c0 + c] = (bf16_t)tile[c * 66 + r];
    }
  } else if (b < 23808) {  // bias_e
    int e = b - 23552;
    float acc = 0.f;
    for (int c = threadIdx.x; c < kCIN; c += 256)
      acc += emb[(size_t)e * kCIN + c] * w_b[c];
#pragma unroll
    for (int o = 32; o > 0; o >>= 1) acc += __shfl_xor(acc, o, 64);
    __syncthreads();
    if ((threadIdx.x & 63) == 0) tile[threadIdx.x >> 6] = acc;
    __syncthreads();
    if (threadIdx.x == 0) biase[e] = tile[0] + tile[1] + tile[2] + tile[3] + emb_b[e];
  } else if (b < 23820) {  // concat biases -> bqkv[3072]
    int i = (b - 23808) * 256 + threadIdx.x;
    if (i < 3072)
      bqkv[i] = i < 1024 ? tb[i] : (i < 2048 ? pb[i - 1024] : gb[i - 2048]);
  } else {  // zero d_out (2M f32 = 524288 float4)
    long i = (long)(b - 23820) * 256 + threadIdx.x;
    ((float4*)out)[i] = make_float4(0.f, 0.f, 0.f, 0.f);
  }
}

// ========== dispatch 2: QKV(384) + S1-tri(144) + M(4) = 532 uniform blocks ========
__global__ __launch_bounds__(512, 2) void k_mega1(const bf16_t* __restrict__ xbf,
                                                  const bf16_t* __restrict__ wqkv,
                                                  const bf16_t* __restrict__ embbf,
                                                  const bf16_t* __restrict__ wwT,
                                                  bf16_t* __restrict__ xtphi,
                                                  bf16_t* __restrict__ S1,
                                                  bf16_t* __restrict__ Mbf,
                                                  const float* __restrict__ bqkv) {
  __shared__ bf16_t lds[65536];  // 128 KiB
  const int tile = blockIdx.x;
  if (tile < 384) {  // xtphi = x @ wqkv^T + bqkv (8192 x 3072, K=2048)
    const int bm = tile & 31, bn = tile >> 5;
    gemm256<0>(lds, xbf, wqkv, xtphi, 2048, 2048, 3072,
               bm * 256, bn * 256, 2048, bqkv);
  } else if (tile < 528) {  // S1[z] = x[z] @ x[z]^T, upper triangular 256-tiles
    int s = tile - 384;
    const int z = s / 36;
    int tt = s % 36, rr = 0;
    while (tt >= 8 - rr) { tt -= 8 - rr; rr++; }
    const bf16_t* Az = xbf + (size_t)z * kT * kCIN;
    gemm256<0>(lds, Az, Az, S1 + (size_t)z * kT * kT, 2048, 2048, 2048,
               rr * 256, (rr + tt) * 256, 2048, nullptr);
  } else {  // M = emb @ w_w (256 x 1024, K=2048)
    const int m = tile - 528;
    gemm256<0>(lds, embbf, wwT, Mbf, 2048, 2048, 1024, 0, m * 256, 2048, nullptr);
  }
}

// ================= dispatch 3: S2 (256 blocks = exactly 1 round) ==================
__global__ __launch_bounds__(512, 2) void k_gemm2(const bf16_t* __restrict__ xtphi,
                                                  bf16_t* __restrict__ S2) {
  __shared__ bf16_t lds[65536];
  const int bid = blockIdx.x;
  const int bm = bid & 7, bn = (bid >> 3) & 7, z = bid >> 6;
  const bf16_t* base = xtphi + (size_t)z * kT * 3072;
  gemm256<0>(lds, base + 1024, base, S2 + (size_t)z * kT * kT, 3072, 3072, 2048,
             bm * 256, bn * 256, 1024, nullptr);
}

// ====== dispatch 4: mirror S1 (1984) + xg-transpose (2048), 256-thread blocks =====
__global__ __launch_bounds__(256) void k_util(bf16_t* __restrict__ S1,
                                              const bf16_t* __restrict__ xtphi,
                                              bf16_t* __restrict__ xgT) {
  __shared__ bf16_t tile[64 * 66];
  const int bid = blockIdx.x;
  const size_t T2 = (size_t)kT * kT;
  if (bid < 1984) {  // mirror S1 upper -> lower (64x64 tiles, p>q)
    int z = bid / 496, t = bid % 496, qq = 0;
    while (t >= 31 - qq) { t -= 31 - qq; qq++; }
    int p = qq + 1 + t;
    const size_t base = (size_t)z * T2;
#pragma unroll
    for (int k = 0; k < 16; k++) {
      int e = k * 256 + threadIdx.x;
      int r = e >> 6, c = e & 63;
      tile[r * 66 + c] = S1[base + (size_t)(qq * 64 + r) * kT + p * 64 + c];
    }
    __syncthreads();
#pragma unroll
    for (int k = 0; k < 16; k++) {
      int e = k * 256 + threadIdx.x;
      int r = e >> 6, c = e & 63;
      S1[base + (size_t)(p * 64 + r) * kT + qq * 64 + c] = tile[c * 66 + r];
    }
  } else {  // xgT[z](h,t) from xg slice of xtphi
    int j = bid - 1984;
    int hb = j & 15, tb2 = (j >> 4) & 31, z = j >> 9;
#pragma unroll
    for (int k = 0; k < 16; k++) {
      int e = k * 256 + threadIdx.x;
      int r = e >> 6, c = e & 63;  // r: t, c: h
      tile[r * 66 + c] = xtphi[(size_t)(z * kT + tb2 * 64 + r) * 3072 + 2048 + hb * 64 + c];
    }
    __syncthreads();
#pragma unroll
    for (int k = 0; k < 16; k++) {
      int e = k * 256 + threadIdx.x;
      int r = e >> 6, c = e & 63;  // r: h, c: t
      xgT[(size_t)z * kHID * kT + (size_t)(hb * 64 + r) * kT + tb2 * 64 + c] = tile[c * 66 + r];
    }
  }
}

// ================= dispatch 5: moca (both softmax passes) =========================
__global__ __launch_bounds__(256) void k_moca(const bf16_t* __restrict__ S1,
                                              const bf16_t* __restrict__ S2,
                                              bf16_t* __restrict__ dst,
                                              const float* __restrict__ rou_w,
                                              const float* __restrict__ rou_b) {
  __shared__ float s[4];
  const int t = blockIdx.x, b = blockIdx.y;
  const size_t T2 = (size_t)kT * kT;
  const bf16_t* src = (b < 2) ? S1 : S2;
  const int pb = (b < 2) ? 2 * b : 2 * (b - 2);
  const bf16_t* rA = src + (size_t)pb * T2 + (size_t)t * kT;
  const bf16_t* rB = rA + T2;
  const int base = threadIdx.x * 8;

  float va[8], vb[8];
  {
    bf16x8 a = *(const bf16x8*)(rA + base);
    bf16x8 bb = *(const bf16x8*)(rB + base);
#pragma unroll
    for (int j = 0; j < 8; j++) { va[j] = (float)a[j]; vb[j] = (float)bb[j]; }
  }
  auto red_max = [&](float v) {
#pragma unroll
    for (int o = 32; o > 0; o >>= 1) v = fmaxf(v, __shfl_xor(v, o, 64));
    __syncthreads();
    if ((threadIdx.x & 63) == 0) s[threadIdx.x >> 6] = v;
    __syncthreads();
    return fmaxf(fmaxf(s[0], s[1]), fmaxf(s[2], s[3]));
  };
  auto red_sum = [&](float v) {
#pragma unroll
    for (int o = 32; o > 0; o >>= 1) v += __shfl_xor(v, o, 64);
    __syncthreads();
    if ((threadIdx.x & 63) == 0) s[threadIdx.x >> 6] = v;
    __syncthreads();
    return (s[0] + s[1]) + (s[2] + s[3]);
  };

  float m = -1e30f, acc;
#pragma unroll
  for (int j = 0; j < 8; j++) m = fmaxf(m, va[j]);
  m = red_max(m); acc = 0.f;
#pragma unroll
  for (int j = 0; j < 8; j++) { va[j] = __expf(va[j] - m); acc += va[j]; }
  float invA = 1.f / red_sum(acc);

  m = -1e30f;
#pragma unroll
  for (int j = 0; j < 8; j++) m = fmaxf(m, vb[j]);
  m = red_max(m); acc = 0.f;
#pragma unroll
  for (int j = 0; j < 8; j++) { vb[j] = __expf(vb[j] - m); acc += vb[j]; }
  float invB = 1.f / red_sum(acc);

  const float r0 = rou_w[0], r1 = rou_w[1], rb = rou_b[0];
#pragma unroll
  for (int j = 0; j < 8; j++) va[j] = r0 * va[j] * invA + r1 * vb[j] * invB + rb;

  m = -1e30f;
#pragma unroll
  for (int j = 0; j < 8; j++) m = fmaxf(m, va[j]);
  m = red_max(m); acc = 0.f;
#pragma unroll
  for (int j = 0; j < 8; j++) { va[j] = __expf(va[j] - m); acc += va[j]; }
  float invC = 1.f / red_sum(acc);

  bf16x8 o;
#pragma unroll
  for (int j = 0; j < 8; j++) o[j] = (bf16_t)(va[j] * invC);
  *(bf16x8*)(dst + (size_t)b * T2 + (size_t)t * kT + base) = o;
}

// ================= dispatch 6: mocab -> mocaT (batched TxT transpose) =============
__global__ __launch_bounds__(256) void k_mocaT(const bf16_t* __restrict__ in,
                                               bf16_t* __restrict__ out) {
  __shared__ bf16_t tile[64 * 66];
  size_t base = (size_t)blockIdx.z * kT * kT;
  int r0 = blockIdx.y * 64, c0 = blockIdx.x * 64;
#pragma unroll
  for (int k = 0; k < 16; k++) {
    int e = k * 256 + threadIdx.x;
    int r = e >> 6, c = e & 63;
    tile[r * 66 + c] = in[base + (size_t)(r0 + r) * kT + c0 + c];
  }
  __syncthreads();
#pragma unroll
  for (int k = 0; k < 16; k++) {
    int e = k * 256 + threadIdx.x;
    int r = e >> 6, c = e & 63;
    out[base + (size_t)(c0 + r) * kT + r0 + c] = tile[c * 66 + r];
  }
}

// ====== dispatch 7: yT GEMM (128) + x@emb^T split-K4 atomic (128) = 256 blocks ====
__global__ __launch_bounds__(512, 2) void k_tail1(const bf16_t* __restrict__ mocaT,
                                                  const bf16_t* __restrict__ xgT,
                                                  bf16_t* __restrict__ yT,
                                                  const bf16_t* __restrict__ xbf,
                                                  const bf16_t* __restrict__ embbf,
                                                  float* __restrict__ out,
                                                  const float* __restrict__ biase) {
  __shared__ bf16_t lds[65536];
  const int bid = blockIdx.x;
  if (bid < 128) {  // yT[z] = mocaT[z] @ xgT[z]^T (2048 x 1024, K=2048)
    const int bm = bid & 7, bn = (bid >> 3) & 3, z = bid >> 5;
    gemm256<0>(lds, mocaT + (size_t)z * kT * kT, xgT + (size_t)z * kHID * kT,
               yT + (size_t)z * kT * kHID, 2048, 2048, 1024,
               bm * 256, bn * 256, 2048, nullptr);
  } else {  // out += x @ emb^T (K=512 slices), + biase on slice 0
    const int r = bid - 128;
    const int bm = r & 31, ks = r >> 5;
    gemm256<2>(lds, xbf + ks * 512, embbf + ks * 512, out, 2048, 2048, 256,
               bm * 256, 0, 512, ks == 0 ? biase : nullptr);
  }
}

// ================= dispatch 8: out += yT @ M^T split-K4 atomic (128) ==============
__global__ __launch_bounds__(512, 2) void k_tail2(const bf16_t* __restrict__ yT,
                                                  const bf16_t* __restrict__ Mbf,
                                                  float* __restrict__ out) {
  __shared__ bf16_t lds[65536];
  const int bid = blockIdx.x;
  const int bm = bid & 31, ks = bid >> 5;
  gemm256<2>(lds, yT + ks * 256, Mbf + ks * 256, out, 1024, 1024, 256,
             bm * 256, 0, 256, nullptr);
}

extern "C" void kernel_launch(void* const* d_in, const int* in_sizes, int n_in,
                              void* d_out, int out_size, void* d_ws, size_t ws_size,
                              hipStream_t stream) {
  const float* x       = (const float*)d_in[0];
  const float* theta_w = (const float*)d_in[1];
  const float* theta_b = (const float*)d_in[2];
  const float* phi_w   = (const float*)d_in[3];
  const float* phi_b   = (const float*)d_in[4];
  const float* g_w     = (const float*)d_in[5];
  const float* g_b     = (const float*)d_in[6];
  const float* rou_w   = (const float*)d_in[7];
  const float* rou_b   = (const float*)d_in[8];
  const float* w_w     = (const float*)d_in[9];
  const float* w_b     = (const float*)d_in[10];
  const float* emb_w   = (const float*)d_in[11];
  const float* emb_b   = (const float*)d_in[12];
  float* out = (float*)d_out;

  char* ws = (char*)d_ws;
  size_t off = 0;
  auto alloc = [&](size_t bytes) -> char* {
    off = (off + 255) & ~(size_t)255;
    char* p = ws + off;
    off += bytes;
    return p;
  };

  const size_t BT = (size_t)kB * kT;   // 8192
  const size_t T2 = (size_t)kT * kT;   // 4M

  bf16_t* xbf   = (bf16_t*)alloc(BT * kCIN * 2);               // 33.5 MB
  bf16_t* wqkv  = (bf16_t*)alloc((size_t)3 * kHID * kCIN * 2); // 12.6 MB
  bf16_t* embbf = (bf16_t*)alloc((size_t)kEMB * kCIN * 2);     // 1.0 MB
  bf16_t* wwT   = (bf16_t*)alloc((size_t)kHID * kCIN * 2);     // 4.2 MB
  bf16_t* xtphi = (bf16_t*)alloc(BT * 3072 * 2);               // 50.3 MB [xt|xphi|xg]
  bf16_t* xgT   = (bf16_t*)alloc((size_t)kB * kHID * kT * 2);  // 16.8 MB
  bf16_t* mocab = (bf16_t*)alloc((size_t)kB * T2 * 2);         // 33.5 MB
  bf16_t* Mbf   = (bf16_t*)alloc((size_t)kEMB * kHID * 2);     // 0.5 MB
  float*  biase = (float*)alloc((size_t)kEMB * 4);
  float*  bqkv  = (float*)alloc((size_t)3072 * 4);
  bf16_t* S1    = (bf16_t*)alloc((size_t)kB * T2 * 2);         // 33.5 MB
  bf16_t* S2    = (bf16_t*)alloc((size_t)kB * T2 * 2);         // 33.5 MB
  // aliases over dead regions:
  bf16_t* mocaT = (bf16_t*)xtphi;  // xtphi dead after k_gemm2 + k_util(xgT)
  bf16_t* yT    = (bf16_t*)S2;     // S2 dead after k_moca (16.8 <= 33.5)

  // 1: prep (casts + wwT + bias_e + bqkv + zero(out))
  k_prep<<<dim3(25868), 256, 0, stream>>>(x, theta_w, phi_w, g_w, emb_w, w_w, w_b,
                                          emb_b, theta_b, phi_b, g_b,
                                          xbf, wqkv, embbf, wwT, biase, bqkv, out);
  // 2: QKV + S1-triangular + M (532 uniform K=2048 tiles)
  k_mega1<<<dim3(532), 512, 0, stream>>>(xbf, wqkv, embbf, wwT, xtphi, S1, Mbf, bqkv);
  // 3: S2
  k_gemm2<<<dim3(256), 512, 0, stream>>>(xtphi, S2);
  // 4: mirror(S1) + xgT
  k_util<<<dim3(4032), 256, 0, stream>>>(S1, xtphi, xgT);
  // 5: moca (both passes)
  k_moca<<<dim3(kT, kB), 256, 0, stream>>>(S1, S2, mocab, rou_w, rou_b);
  // 6: mocaT (overwrites dead xtphi)
  k_mocaT<<<dim3(32, 32, kB), 256, 0, stream>>>(mocab, mocaT);
  // 7: yT GEMM (over dead S2) + x@emb^T split-K atomic
  k_tail1<<<dim3(256), 512, 0, stream>>>(mocaT, xgT, yT, xbf, embbf, out, biase);
  // 8: out += yT @ M^T split-K atomic
  k_tail2<<<dim3(128), 512, 0, stream>>>(yT, Mbf, out);
}